// Round 1
// baseline (5029.409 us; speedup 1.0000x reference)
//
#include <hip/hip_runtime.h>
#include <cstdint>
#include <cstddef>

// Problem: B=64, T=512, D_IN=1024, UNITS=1024
//   phase 1: xk = x @ kernel  -> written into d_out  [32768 x 1024]
//   phase 2: persistent scan kernel, in-place on d_out:
//            h_t = relu(xk_t + h_{t-1} @ R)
//
// Phase-2 geometry (R4): 4 clusters (16 batches) x 8 col-group WGs (128 cols)
//   = 32 WGs x 512 threads (8 waves). Per wave: k-slice of 128 (k-split 8),
//   all 8 n-tiles; W persistent in 128 VGPRs.
// Sync protocol (R4): per-WAVE release flags (plain sc0 sc1 stores, no
//   atomics). 64 flags per cluster = one coalesced 256B poll load per wave;
//   every wave polls independently (no tid0 funnel, no release barrier).
//   Only ONE __syncthreads per step (red write->read); the write-after-read
//   hazard is covered by the flag poll itself (flag t+1 is stored only
//   after red reads of step t completed).
// h exchanged via sc0 sc1 ld/st as before (proven protocol): stores ->
//   vmcnt(0) -> flag store; consumers poll flags >= t then load frags.

typedef __attribute__((ext_vector_type(8))) short short8;
typedef __attribute__((ext_vector_type(4))) float f32x4;

static __device__ __forceinline__ unsigned short f2bf_rne(float f) {
  unsigned u = __float_as_uint(f);
  u += 0x7fffu + ((u >> 16) & 1u);
  return (unsigned short)(u >> 16);
}

static __device__ __forceinline__ void wait_vm0() {
  asm volatile("s_waitcnt vmcnt(0)" ::: "memory");
}
static __device__ __forceinline__ unsigned ld_flag_cc(const unsigned int* p) {
  unsigned v;
  asm volatile("global_load_dword %0, %1, off sc0 sc1\n\t"
               "s_waitcnt vmcnt(0)"
               : "=v"(v) : "v"(p) : "memory");
  return v;
}
static __device__ __forceinline__ void st_flag_cc(unsigned int* p, unsigned v) {
  asm volatile("global_store_dword %0, %1, off sc0 sc1"
               :: "v"(p), "v"(v) : "memory");
}
static __device__ __forceinline__ void st_g64_cc(unsigned short* p, unsigned long long v) {
  asm volatile("global_store_dwordx2 %0, %1, off sc0 sc1"
               :: "v"(p), "v"(v) : "memory");
}

// ---------------------------------------------------------------- phase 1
__global__ __launch_bounds__(256) void xproj_kernel(const float* __restrict__ x,
                                                    const float* __restrict__ kern,
                                                    float* __restrict__ out) {
  __shared__ unsigned short Abuf[128 * 40];
  __shared__ unsigned short Bbuf[128 * 40];
  const int tid = threadIdx.x;
  const int lane = tid & 63;
  const int wv = tid >> 6;
  const int q = lane >> 4;
  const int lr = lane & 15;
  const int wm = (wv >> 1) * 64;
  const int wn = (wv & 1) * 64;
  const long rowbase = (long)blockIdx.y * 128;
  const int colbase = blockIdx.x * 128;

  f32x4 acc[4][4];
#pragma unroll
  for (int i = 0; i < 4; i++)
#pragma unroll
    for (int j = 0; j < 4; j++) acc[i][j] = (f32x4)0.f;

  for (int kb = 0; kb < 1024; kb += 32) {
#pragma unroll
    for (int r = 0; r < 4; ++r) {
      int idx = tid + r * 256;
      int m = idx >> 3;
      int kk = (idx & 7) * 4;
      float4 v = *(const float4*)(x + (rowbase + m) * 1024 + kb + kk);
      ushort4 w4;
      w4.x = f2bf_rne(v.x); w4.y = f2bf_rne(v.y);
      w4.z = f2bf_rne(v.z); w4.w = f2bf_rne(v.w);
      *(ushort4*)&Abuf[m * 40 + kk] = w4;
    }
#pragma unroll
    for (int r = 0; r < 4; ++r) {
      int idx = tid + r * 256;
      int kr = idx >> 5;
      int nn = (idx & 31) * 4;
      float4 v = *(const float4*)(kern + (long)(kb + kr) * 1024 + colbase + nn);
      Bbuf[(nn + 0) * 40 + kr] = f2bf_rne(v.x);
      Bbuf[(nn + 1) * 40 + kr] = f2bf_rne(v.y);
      Bbuf[(nn + 2) * 40 + kr] = f2bf_rne(v.z);
      Bbuf[(nn + 3) * 40 + kr] = f2bf_rne(v.w);
    }
    __syncthreads();
    short8 af[4], bfr[4];
#pragma unroll
    for (int i = 0; i < 4; i++)
      af[i] = *(const short8*)&Abuf[(wm + i * 16 + lr) * 40 + q * 8];
#pragma unroll
    for (int j = 0; j < 4; j++)
      bfr[j] = *(const short8*)&Bbuf[(wn + j * 16 + lr) * 40 + q * 8];
#pragma unroll
    for (int i = 0; i < 4; i++)
#pragma unroll
      for (int j = 0; j < 4; j++)
        acc[i][j] = __builtin_amdgcn_mfma_f32_16x16x32_bf16(af[i], bfr[j], acc[i][j], 0, 0, 0);
    __syncthreads();
  }
#pragma unroll
  for (int i = 0; i < 4; i++) {
#pragma unroll
    for (int r = 0; r < 4; r++) {
      long row = rowbase + wm + i * 16 + q * 4 + r;
      float* op = out + row * 1024 + colbase + wn + lr;
#pragma unroll
      for (int j = 0; j < 4; j++) op[j * 16] = acc[i][j][r];
    }
  }
}

// ---------------------------------------------------------------- phase 2
// hbuf layout (u16): [parity 2][part hi/lo 2][cluster 4][16384]
//   element (m,k) at (k>>3)*128 + m*8 + (k&7)  -> A-frag dwordx4-ready.
// flags layout (u32): [cluster 4][64]  (64 = cg(8) * wave(8)), value = t+1
//   after that wave's h_t stores have drained at the coherence point.
__global__ __launch_bounds__(512, 2) void rnn_scan_kernel(const float* __restrict__ R,
                                                          float* __restrict__ out,
                                                          unsigned short* __restrict__ hbuf,
                                                          unsigned int* __restrict__ flags) {
  const int tid = threadIdx.x;
  const int lane = tid & 63;
  const int wv = tid >> 6;        // k-slice 0..7 (128 k each)
  const int q = lane >> 4;
  const int lr = lane & 15;
  const int cluster = blockIdx.x & 3;
  const int cg = blockIdx.x >> 2; // col-group 0..7 (128 cols each)
  const int colbase = cg * 128;

  // persistent W fragments: B[k][n] frag: lane n=lr, k = wv*128 + cc*32 + q*8+j
  short8 w[8][4];                 // 128 VGPRs
#pragma unroll
  for (int nt = 0; nt < 8; nt++) {
    const int col = colbase + nt * 16 + lr;
#pragma unroll
    for (int cc = 0; cc < 4; cc++) {
      const int k0 = wv * 128 + cc * 32 + q * 8;
      short8 t8;
#pragma unroll
      for (int j = 0; j < 8; j++)
        t8[j] = (short)f2bf_rne(R[(long)(k0 + j) * 1024 + col]);
      w[nt][cc] = t8;
    }
  }

  __shared__ float red[8 * 8 * 64 * 4];  // [kq][nt][lane][reg] 64 KB

  // per-thread output mapping: m = tid>>5 (0..15), 4 consecutive cols
  const int m = tid >> 5;
  const int cw0 = (tid & 31) * 4;             // col within WG, 4-aligned
  const int kglob = colbase + cw0;            // global unit index
  const int hoff = (kglob >> 3) * 128 + m * 8 + (kglob & 7);  // 4 consec u16
  const int off0 = (wv * 16 + q) * 128 + lr * 8;              // frag-load base
  const int ntr = cw0 >> 4;                   // red-read ntile
  const int Lb = (cw0 & 15) + ((m >> 2) << 4);
  const int rr = m & 3;

  unsigned int* myflags = flags + cluster * 64;
  unsigned int* myflag = myflags + cg * 8 + wv;
  float* myout = out + ((long)(cluster * 16 + m) * 512) * 1024 + kglob;

  for (int t = 0; t < 512; ++t) {
    // xk prefetch: independent of flags, overlaps the poll round trip
    const float4 xkv = *(const float4*)(myout + (long)t * 1024);
    f32x4 acc[8];
#pragma unroll
    for (int nt = 0; nt < 8; nt++) acc[nt] = (f32x4)0.f;

    if (t > 0) {
      // ---- poll: all 64 lanes read all 64 flags (one coalesced 256B load)
      const unsigned target = (unsigned)t;
      unsigned f = ld_flag_cc(myflags + lane);
      while (__ballot(f < target) != 0ull) {
        f = ld_flag_cc(myflags + lane);
      }
      // ---- h_{t-1} fragment loads (hi first, lo second; vmcnt(4) lets
      //      hi-MFMAs overlap the lo stream)
      const unsigned short* a0 =
          hbuf + (size_t)((((t - 1) & 1) * 2 + 0) * 4 + cluster) * 16384 + off0;
      const unsigned short* b0 =
          hbuf + (size_t)((((t - 1) & 1) * 2 + 1) * 4 + cluster) * 16384 + off0;
      short8 ah[4], al[4];
      asm volatile(
          "global_load_dwordx4 %0, %8, off sc0 sc1\n\t"
          "global_load_dwordx4 %1, %8, off offset:1024 sc0 sc1\n\t"
          "global_load_dwordx4 %2, %8, off offset:2048 sc0 sc1\n\t"
          "global_load_dwordx4 %3, %8, off offset:3072 sc0 sc1\n\t"
          "global_load_dwordx4 %4, %9, off sc0 sc1\n\t"
          "global_load_dwordx4 %5, %9, off offset:1024 sc0 sc1\n\t"
          "global_load_dwordx4 %6, %9, off offset:2048 sc0 sc1\n\t"
          "global_load_dwordx4 %7, %9, off offset:3072 sc0 sc1\n\t"
          "s_waitcnt vmcnt(4)"
          : "=&v"(ah[0]), "=&v"(ah[1]), "=&v"(ah[2]), "=&v"(ah[3]),
            "=&v"(al[0]), "=&v"(al[1]), "=&v"(al[2]), "=&v"(al[3])
          : "v"(a0), "v"(b0)
          : "memory");
#pragma unroll
      for (int cc = 0; cc < 4; cc++)
#pragma unroll
        for (int nt = 0; nt < 8; nt++)
          acc[nt] = __builtin_amdgcn_mfma_f32_16x16x32_bf16(ah[cc], w[nt][cc], acc[nt], 0, 0, 0);
      // al regs pass through this asm so lo-MFMAs cannot hoist above the wait
      asm volatile("s_waitcnt vmcnt(0)"
                   : "+v"(al[0]), "+v"(al[1]), "+v"(al[2]), "+v"(al[3])
                   :: "memory");
#pragma unroll
      for (int cc = 0; cc < 4; cc++)
#pragma unroll
        for (int nt = 0; nt < 8; nt++)
          acc[nt] = __builtin_amdgcn_mfma_f32_16x16x32_bf16(al[cc], w[nt][cc], acc[nt], 0, 0, 0);
    }

    // ---- 8-way k-split reduction through LDS (single barrier per step;
    //      the t+1 flag poll covers the write-after-read hazard)
#pragma unroll
    for (int nt = 0; nt < 8; nt++)
      *(f32x4*)&red[((wv * 8 + nt) * 64 + lane) * 4] = acc[nt];
    __syncthreads();

    const float xarr[4] = {xkv.x, xkv.y, xkv.z, xkv.w};
    float hv[4];
    unsigned long long hpk = 0ull, lpk = 0ull;
#pragma unroll
    for (int j = 0; j < 4; ++j) {
      float s = 0.f;
#pragma unroll
      for (int kq = 0; kq < 8; ++kq)
        s += red[((kq * 8 + ntr) * 64 + Lb + j) * 4 + rr];
      float h = fmaxf(s + xarr[j], 0.0f);
      hv[j] = h;
      unsigned short hi = f2bf_rne(h);
      float hf = __uint_as_float(((unsigned)hi) << 16);
      unsigned short lo = f2bf_rne(h - hf);
      hpk |= (unsigned long long)hi << (16 * j);
      lpk |= (unsigned long long)lo << (16 * j);
    }
    // publish h_t (hi/lo), drain, release flag; out store AFTER the flag so
    // its ack is off the release path (out is private to this thread).
    st_g64_cc(hbuf + (size_t)(((t & 1) * 2 + 0) * 4 + cluster) * 16384 + hoff, hpk);
    st_g64_cc(hbuf + (size_t)(((t & 1) * 2 + 1) * 4 + cluster) * 16384 + hoff, lpk);
    wait_vm0();
    if (lane == 0) st_flag_cc(myflag, (unsigned)(t + 1));
    float4 hq;
    hq.x = hv[0]; hq.y = hv[1]; hq.z = hv[2]; hq.w = hv[3];
    *(float4*)(myout + (long)t * 1024) = hq;
  }
}

extern "C" void kernel_launch(void* const* d_in, const int* in_sizes, int n_in,
                              void* d_out, int out_size, void* d_ws, size_t ws_size,
                              hipStream_t stream) {
  const float* x = (const float*)d_in[0];
  const float* kern = (const float*)d_in[1];
  const float* R = (const float*)d_in[2];
  float* out = (float*)d_out;

  // ws: [0, 512KB) h ping-pong hi/lo buffers; [512KB, +1KB) release flags
  unsigned short* hbuf = (unsigned short*)d_ws;
  unsigned int* flags = (unsigned int*)((char*)d_ws + (size_t)2 * 2 * 4 * 16384 * sizeof(unsigned short));
  hipMemsetAsync(flags, 0, 1024, stream);

  dim3 g1(8, 256), b1(256);
  xproj_kernel<<<g1, b1, 0, stream>>>(x, kern, out);
  rnn_scan_kernel<<<32, 512, 0, stream>>>(R, out, hbuf, flags);
}

// Round 2
// 2656.012 us; speedup vs baseline: 1.8936x; 1.8936x over previous
//
#include <hip/hip_runtime.h>
#include <cstdint>
#include <cstddef>

// Problem: B=64, T=512, D_IN=1024, UNITS=1024
//   phase 1: xk = x @ kernel  -> written into d_out  [32768 x 1024]
//   phase 2: persistent scan kernel, in-place on d_out:
//            h_t = relu(xk_t + h_{t-1} @ R)
//
// Phase-2 geometry (R5): 4 clusters (16 batches) x 8 col-group WGs (128 cols)
//   = 32 WGs x 512 threads (8 waves). Per wave: k-slice of 128 (k-split 8),
//   all 8 n-tiles; W persistent in 128 VGPRs.
// R5 fixes vs R4 (which regressed 1837->4536 us):
//   (a) reduction reads were 16-way bank-conflicted (SQ_LDS_BANK_CONFLICT
//       1.26e8): thread now owns (1 col, 4 rows) so the k-split reduce is
//       8x ds_read_b128 of contiguous f32x4 (the MFMA C-layout packs the
//       4 rows m=mg*4+r of one column into one lane's 4 regs). Conflict-free.
//   (b) all-wave flag polling (256 waves spinning vmcnt(0) system-scope
//       loads on the same 1KB) contended the coherence point: now only
//       wave 0 polls (one coalesced 256B load), others wait at a local
//       __syncthreads. 32 pollers total.
// Sync protocol otherwise as R4: per-WAVE release flags (plain sc0 sc1
//   stores, no atomics), value t+1 stored after that wave's h_t stores
//   drained (vmcnt0). Consumers at step t need flags >= t.

typedef __attribute__((ext_vector_type(8))) short short8;
typedef __attribute__((ext_vector_type(4))) float f32x4;

static __device__ __forceinline__ unsigned short f2bf_rne(float f) {
  unsigned u = __float_as_uint(f);
  u += 0x7fffu + ((u >> 16) & 1u);
  return (unsigned short)(u >> 16);
}

static __device__ __forceinline__ void wait_vm0() {
  asm volatile("s_waitcnt vmcnt(0)" ::: "memory");
}
static __device__ __forceinline__ unsigned ld_flag_cc(const unsigned int* p) {
  unsigned v;
  asm volatile("global_load_dword %0, %1, off sc0 sc1\n\t"
               "s_waitcnt vmcnt(0)"
               : "=v"(v) : "v"(p) : "memory");
  return v;
}
static __device__ __forceinline__ void st_flag_cc(unsigned int* p, unsigned v) {
  asm volatile("global_store_dword %0, %1, off sc0 sc1"
               :: "v"(p), "v"(v) : "memory");
}
static __device__ __forceinline__ void st_g16_cc(unsigned short* p, unsigned short val) {
  unsigned v32 = val;
  asm volatile("global_store_short %0, %1, off sc0 sc1"
               :: "v"(p), "v"(v32) : "memory");
}

// ---------------------------------------------------------------- phase 1
__global__ __launch_bounds__(256) void xproj_kernel(const float* __restrict__ x,
                                                    const float* __restrict__ kern,
                                                    float* __restrict__ out) {
  __shared__ unsigned short Abuf[128 * 40];
  __shared__ unsigned short Bbuf[128 * 40];
  const int tid = threadIdx.x;
  const int lane = tid & 63;
  const int wv = tid >> 6;
  const int q = lane >> 4;
  const int lr = lane & 15;
  const int wm = (wv >> 1) * 64;
  const int wn = (wv & 1) * 64;
  const long rowbase = (long)blockIdx.y * 128;
  const int colbase = blockIdx.x * 128;

  f32x4 acc[4][4];
#pragma unroll
  for (int i = 0; i < 4; i++)
#pragma unroll
    for (int j = 0; j < 4; j++) acc[i][j] = (f32x4)0.f;

  for (int kb = 0; kb < 1024; kb += 32) {
#pragma unroll
    for (int r = 0; r < 4; ++r) {
      int idx = tid + r * 256;
      int m = idx >> 3;
      int kk = (idx & 7) * 4;
      float4 v = *(const float4*)(x + (rowbase + m) * 1024 + kb + kk);
      ushort4 w4;
      w4.x = f2bf_rne(v.x); w4.y = f2bf_rne(v.y);
      w4.z = f2bf_rne(v.z); w4.w = f2bf_rne(v.w);
      *(ushort4*)&Abuf[m * 40 + kk] = w4;
    }
#pragma unroll
    for (int r = 0; r < 4; ++r) {
      int idx = tid + r * 256;
      int kr = idx >> 5;
      int nn = (idx & 31) * 4;
      float4 v = *(const float4*)(kern + (long)(kb + kr) * 1024 + colbase + nn);
      Bbuf[(nn + 0) * 40 + kr] = f2bf_rne(v.x);
      Bbuf[(nn + 1) * 40 + kr] = f2bf_rne(v.y);
      Bbuf[(nn + 2) * 40 + kr] = f2bf_rne(v.z);
      Bbuf[(nn + 3) * 40 + kr] = f2bf_rne(v.w);
    }
    __syncthreads();
    short8 af[4], bfr[4];
#pragma unroll
    for (int i = 0; i < 4; i++)
      af[i] = *(const short8*)&Abuf[(wm + i * 16 + lr) * 40 + q * 8];
#pragma unroll
    for (int j = 0; j < 4; j++)
      bfr[j] = *(const short8*)&Bbuf[(wn + j * 16 + lr) * 40 + q * 8];
#pragma unroll
    for (int i = 0; i < 4; i++)
#pragma unroll
      for (int j = 0; j < 4; j++)
        acc[i][j] = __builtin_amdgcn_mfma_f32_16x16x32_bf16(af[i], bfr[j], acc[i][j], 0, 0, 0);
    __syncthreads();
  }
#pragma unroll
  for (int i = 0; i < 4; i++) {
#pragma unroll
    for (int r = 0; r < 4; r++) {
      long row = rowbase + wm + i * 16 + q * 4 + r;
      float* op = out + row * 1024 + colbase + wn + lr;
#pragma unroll
      for (int j = 0; j < 4; j++) op[j * 16] = acc[i][j][r];
    }
  }
}

// ---------------------------------------------------------------- phase 2
// hbuf layout (u16): [parity 2][part hi/lo 2][cluster 4][16384]
//   element (m,k) at (k>>3)*128 + m*8 + (k&7)  -> A-frag dwordx4-ready.
// flags layout (u32): [cluster 4][64]  (64 = cg(8) * wave(8)), value = t+1
//   after that wave's h_t stores have drained at the coherence point.
__global__ __launch_bounds__(512, 2) void rnn_scan_kernel(const float* __restrict__ R,
                                                          float* __restrict__ out,
                                                          unsigned short* __restrict__ hbuf,
                                                          unsigned int* __restrict__ flags) {
  const int tid = threadIdx.x;
  const int lane = tid & 63;
  const int wv = tid >> 6;        // k-slice 0..7 (128 k each)
  const int q = lane >> 4;
  const int lr = lane & 15;
  const int cluster = blockIdx.x & 3;
  const int cg = blockIdx.x >> 2; // col-group 0..7 (128 cols each)
  const int colbase = cg * 128;

  // persistent W fragments: B[k][n] frag: lane n=lr, k = wv*128 + cc*32 + q*8+j
  short8 w[8][4];                 // 128 VGPRs
#pragma unroll
  for (int nt = 0; nt < 8; nt++) {
    const int col = colbase + nt * 16 + lr;
#pragma unroll
    for (int cc = 0; cc < 4; cc++) {
      const int k0 = wv * 128 + cc * 32 + q * 8;
      short8 t8;
#pragma unroll
      for (int j = 0; j < 8; j++)
        t8[j] = (short)f2bf_rne(R[(long)(k0 + j) * 1024 + col]);
      w[nt][cc] = t8;
    }
  }

  __shared__ float red[8 * 8 * 64 * 4];  // [kq*8+nt][lane][r] 64 KB

  // ---- column-ownership output mapping: thread owns (col n, rows mg*4+0..3)
  const int nw = tid & 127;              // col within WG
  const int mg = tid >> 7;               // row group 0..3
  const int kglob = colbase + nw;        // global unit (= hbuf k) index
  const int hbase = (kglob >> 3) * 128 + (kglob & 7) + mg * 32;  // + r*8
  const int ntr = nw >> 4;               // C-tile of my column
  const int rlane = mg * 16 + (nw & 15); // C-lane holding my f32x4
  const int off0 = (wv * 16 + q) * 128 + lr * 8;  // A-frag load base (u16)

  unsigned int* myflags = flags + cluster * 64;
  unsigned int* myflag = myflags + cg * 8 + wv;
  float* op0 = out + ((long)(cluster * 16 + mg * 4 + 0) * 512) * 1024 + kglob;
  float* op1 = out + ((long)(cluster * 16 + mg * 4 + 1) * 512) * 1024 + kglob;
  float* op2 = out + ((long)(cluster * 16 + mg * 4 + 2) * 512) * 1024 + kglob;
  float* op3 = out + ((long)(cluster * 16 + mg * 4 + 3) * 512) * 1024 + kglob;

  for (int t = 0; t < 512; ++t) {
    const long tOff = (long)t * 1024;
    // xk prefetch (plain cached loads, coalesced per row across the wave):
    // issued before the poll barrier so the RT hides under the wait.
    const float xk0 = op0[tOff];
    const float xk1 = op1[tOff];
    const float xk2 = op2[tOff];
    const float xk3 = op3[tOff];

    f32x4 acc[8];
#pragma unroll
    for (int nt = 0; nt < 8; nt++) acc[nt] = (f32x4)0.f;

    if (t > 0) {
      // ---- wave 0 polls the 64 per-wave flags; others wait at the barrier
      if (wv == 0) {
        const unsigned target = (unsigned)t;
        unsigned f = ld_flag_cc(myflags + lane);
        while (__ballot(f < target) != 0ull) {
          f = ld_flag_cc(myflags + lane);
        }
      }
      __syncthreads();
      // ---- h_{t-1} fragment loads (hi first, lo second; vmcnt(4) lets
      //      hi-MFMAs overlap the lo stream)
      const unsigned short* a0 =
          hbuf + (size_t)((((t - 1) & 1) * 2 + 0) * 4 + cluster) * 16384 + off0;
      const unsigned short* b0 =
          hbuf + (size_t)((((t - 1) & 1) * 2 + 1) * 4 + cluster) * 16384 + off0;
      short8 ah[4], al[4];
      asm volatile(
          "global_load_dwordx4 %0, %8, off sc0 sc1\n\t"
          "global_load_dwordx4 %1, %8, off offset:1024 sc0 sc1\n\t"
          "global_load_dwordx4 %2, %8, off offset:2048 sc0 sc1\n\t"
          "global_load_dwordx4 %3, %8, off offset:3072 sc0 sc1\n\t"
          "global_load_dwordx4 %4, %9, off sc0 sc1\n\t"
          "global_load_dwordx4 %5, %9, off offset:1024 sc0 sc1\n\t"
          "global_load_dwordx4 %6, %9, off offset:2048 sc0 sc1\n\t"
          "global_load_dwordx4 %7, %9, off offset:3072 sc0 sc1\n\t"
          "s_waitcnt vmcnt(4)"
          : "=&v"(ah[0]), "=&v"(ah[1]), "=&v"(ah[2]), "=&v"(ah[3]),
            "=&v"(al[0]), "=&v"(al[1]), "=&v"(al[2]), "=&v"(al[3])
          : "v"(a0), "v"(b0)
          : "memory");
#pragma unroll
      for (int cc = 0; cc < 4; cc++)
#pragma unroll
        for (int nt = 0; nt < 8; nt++)
          acc[nt] = __builtin_amdgcn_mfma_f32_16x16x32_bf16(ah[cc], w[nt][cc], acc[nt], 0, 0, 0);
      // al regs pass through this asm so lo-MFMAs cannot hoist above the wait
      asm volatile("s_waitcnt vmcnt(0)"
                   : "+v"(al[0]), "+v"(al[1]), "+v"(al[2]), "+v"(al[3])
                   :: "memory");
#pragma unroll
      for (int cc = 0; cc < 4; cc++)
#pragma unroll
        for (int nt = 0; nt < 8; nt++)
          acc[nt] = __builtin_amdgcn_mfma_f32_16x16x32_bf16(al[cc], w[nt][cc], acc[nt], 0, 0, 0);
    }

    // ---- 8-way k-split reduction through LDS.
    // writes: b128, lanes consecutive 16B -> streaming minimum, no conflicts
#pragma unroll
    for (int nt = 0; nt < 8; nt++)
      *(f32x4*)&red[((wv * 8 + nt) * 64 + lane) * 4] = acc[nt];
    __syncthreads();
    // reads: one f32x4 per k-slice (4 rows of my column live in one lane's
    // 4 regs per the 16x16 C-layout). Bank-quads balanced -> conflict-free.
    f32x4 s = *(const f32x4*)&red[((0 * 8 + ntr) * 64 + rlane) * 4];
#pragma unroll
    for (int kq = 1; kq < 8; ++kq)
      s += *(const f32x4*)&red[((kq * 8 + ntr) * 64 + rlane) * 4];

    const float xarr[4] = {xk0, xk1, xk2, xk3};
    float hv[4];
    unsigned short hpk[4], lpk[4];
#pragma unroll
    for (int r = 0; r < 4; ++r) {
      float h = fmaxf(s[r] + xarr[r], 0.0f);
      hv[r] = h;
      unsigned short hi = f2bf_rne(h);
      float hf = __uint_as_float(((unsigned)hi) << 16);
      hpk[r] = hi;
      lpk[r] = f2bf_rne(h - hf);
    }
    // publish h_t (hi/lo), drain, release flag; out stores AFTER the flag so
    // their ack is off the release path (out is private to this thread).
    unsigned short* hb = hbuf + (size_t)(((t & 1) * 2 + 0) * 4 + cluster) * 16384 + hbase;
    unsigned short* lb = hbuf + (size_t)(((t & 1) * 2 + 1) * 4 + cluster) * 16384 + hbase;
#pragma unroll
    for (int r = 0; r < 4; ++r) {
      st_g16_cc(hb + r * 8, hpk[r]);
      st_g16_cc(lb + r * 8, lpk[r]);
    }
    wait_vm0();
    if (lane == 0) st_flag_cc(myflag, (unsigned)(t + 1));
    op0[tOff] = hv[0];
    op1[tOff] = hv[1];
    op2[tOff] = hv[2];
    op3[tOff] = hv[3];
  }
}

extern "C" void kernel_launch(void* const* d_in, const int* in_sizes, int n_in,
                              void* d_out, int out_size, void* d_ws, size_t ws_size,
                              hipStream_t stream) {
  const float* x = (const float*)d_in[0];
  const float* kern = (const float*)d_in[1];
  const float* R = (const float*)d_in[2];
  float* out = (float*)d_out;

  // ws: [0, 512KB) h ping-pong hi/lo buffers; [512KB, +1KB) release flags
  unsigned short* hbuf = (unsigned short*)d_ws;
  unsigned int* flags = (unsigned int*)((char*)d_ws + (size_t)2 * 2 * 4 * 16384 * sizeof(unsigned short));
  hipMemsetAsync(flags, 0, 1024, stream);

  dim3 g1(8, 256), b1(256);
  xproj_kernel<<<g1, b1, 0, stream>>>(x, kern, out);
  rnn_scan_kernel<<<32, 512, 0, stream>>>(R, out, hbuf, flags);
}

// Round 4
// 2401.309 us; speedup vs baseline: 2.0944x; 1.1061x over previous
//
#include <hip/hip_runtime.h>
#include <cstdint>
#include <cstddef>

// Problem: B=64, T=512, D_IN=1024, UNITS=1024
//   phase 1: xk = x @ kernel  -> written into d_out  [32768 x 1024]
//   phase 2: persistent scan kernel, in-place on d_out:
//            h_t = relu(xk_t + h_{t-1} @ R)
//
// R7: flagless data-embedded-tag rendezvous at the coherence point.
//   R5's chain was ~3.5 serial CP round-trips/step: store-ack drain ->
//   flag store -> flag poll RT -> h-frag load RT. R7 removes the drain,
//   the flag, and the separate frag load: h is published as 16B units
//   [hi bf16 x4 | lo bf16 x4] (one dwordx4, single CP transaction).
//   h>=0 (relu) so the 4 hi sign bits carry a 4-bit generation tag
//   (t>>1)&15. Consumers poll their OWN units (sc0 sc1 dwordx4) until
//   all tags match, strip signs, and feed MFMA directly: ~1.5 RT/step.
//   Tag safety: slot parity t&1, gen mod 16 disambiguates the previous
//   generation (skew is provably <=1 step); virgin/stale workspace is
//   handled by memset 0xFF (reads as tag 15; tags 0..14 used first) and
//   prior-run leftovers end at tag 15 too.
//   Torn units (dword-granularity) fail their own tag check -> retried.
// Geometry: 4 clusters (16 batches) x 8 col-group WGs (128 cols), 512 thr
//   = 8 waves (k-split 4 x n-half 2); W persistent in 128 VGPRs/wave.
//   Per-wave independent polling (no wave0 funnel, no pre-load barrier).
//   Producer: column-owned reduce -> LDS transpose (xbuf) -> row-owned
//   16B unit stores (coalesced 1KB/wave).

typedef __attribute__((ext_vector_type(8))) short short8;
typedef __attribute__((ext_vector_type(4))) float f32x4;
typedef __attribute__((ext_vector_type(4))) unsigned int u32x4;

static __device__ __forceinline__ unsigned short f2bf_rne(float f) {
  unsigned u = __float_as_uint(f);
  u += 0x7fffu + ((u >> 16) & 1u);
  return (unsigned short)(u >> 16);
}

// ---------------------------------------------------------------- phase 1
__global__ __launch_bounds__(256) void xproj_kernel(const float* __restrict__ x,
                                                    const float* __restrict__ kern,
                                                    float* __restrict__ out) {
  __shared__ unsigned short Abuf[128 * 40];
  __shared__ unsigned short Bbuf[128 * 40];
  const int tid = threadIdx.x;
  const int lane = tid & 63;
  const int wv = tid >> 6;
  const int q = lane >> 4;
  const int lr = lane & 15;
  const int wm = (wv >> 1) * 64;
  const int wn = (wv & 1) * 64;
  const long rowbase = (long)blockIdx.y * 128;
  const int colbase = blockIdx.x * 128;

  f32x4 acc[4][4];
#pragma unroll
  for (int i = 0; i < 4; i++)
#pragma unroll
    for (int j = 0; j < 4; j++) acc[i][j] = (f32x4)0.f;

  for (int kb = 0; kb < 1024; kb += 32) {
#pragma unroll
    for (int r = 0; r < 4; ++r) {
      int idx = tid + r * 256;
      int m = idx >> 3;
      int kk = (idx & 7) * 4;
      float4 v = *(const float4*)(x + (rowbase + m) * 1024 + kb + kk);
      ushort4 w4;
      w4.x = f2bf_rne(v.x); w4.y = f2bf_rne(v.y);
      w4.z = f2bf_rne(v.z); w4.w = f2bf_rne(v.w);
      *(ushort4*)&Abuf[m * 40 + kk] = w4;
    }
#pragma unroll
    for (int r = 0; r < 4; ++r) {
      int idx = tid + r * 256;
      int kr = idx >> 5;
      int nn = (idx & 31) * 4;
      float4 v = *(const float4*)(kern + (long)(kb + kr) * 1024 + colbase + nn);
      Bbuf[(nn + 0) * 40 + kr] = f2bf_rne(v.x);
      Bbuf[(nn + 1) * 40 + kr] = f2bf_rne(v.y);
      Bbuf[(nn + 2) * 40 + kr] = f2bf_rne(v.z);
      Bbuf[(nn + 3) * 40 + kr] = f2bf_rne(v.w);
    }
    __syncthreads();
    short8 af[4], bfr[4];
#pragma unroll
    for (int i = 0; i < 4; i++)
      af[i] = *(const short8*)&Abuf[(wm + i * 16 + lr) * 40 + q * 8];
#pragma unroll
    for (int j = 0; j < 4; j++)
      bfr[j] = *(const short8*)&Bbuf[(wn + j * 16 + lr) * 40 + q * 8];
#pragma unroll
    for (int i = 0; i < 4; i++)
#pragma unroll
      for (int j = 0; j < 4; j++)
        acc[i][j] = __builtin_amdgcn_mfma_f32_16x16x32_bf16(af[i], bfr[j], acc[i][j], 0, 0, 0);
    __syncthreads();
  }
#pragma unroll
  for (int i = 0; i < 4; i++) {
#pragma unroll
    for (int r = 0; r < 4; r++) {
      long row = rowbase + wm + i * 16 + q * 4 + r;
      float* op = out + row * 1024 + colbase + wn + lr;
#pragma unroll
      for (int j = 0; j < 4; j++) op[j * 16] = acc[i][j][r];
    }
  }
}

// ---------------------------------------------------------------- phase 2
// hbuf: 16B units. Block per (slot 2, cluster 4): 64KB = 256 kq x 16 m.
//   unit (m, kq) at byte ((kq*16 + m) * 16) within its block; contents
//   dwords [hi(4k..4k+1), hi(4k+2..3), lo(4k..1), lo(4k+2..3)] for row m.
__global__ __launch_bounds__(512, 2) void rnn_scan_kernel(const float* __restrict__ R,
                                                          float* __restrict__ out,
                                                          unsigned char* __restrict__ hbuf) {
  const int tid = threadIdx.x;
  const int lane = tid & 63;
  const int wv = tid >> 6;
  const int q = lane >> 4;
  const int lr = lane & 15;
  const int cluster = blockIdx.x & 3;
  const int cg = blockIdx.x >> 2;       // col-group 0..7 (128 cols each)
  const int ks = wv & 3;                // k-slice 0..3 (256 k each)
  const int nh = wv >> 2;               // n-half 0..1 (64 cols each)
  const int colbase = cg * 128;

  // persistent W fragments: B[k][n]: lane n=lr, k = ks*256 + cc*32 + q*8+j
  short8 w[4][8];                       // 128 VGPRs
#pragma unroll
  for (int nt = 0; nt < 4; nt++) {
    const int col = colbase + nh * 64 + nt * 16 + lr;
#pragma unroll
    for (int cc = 0; cc < 8; cc++) {
      const int k0 = ks * 256 + cc * 32 + q * 8;
      short8 t8;
#pragma unroll
      for (int j = 0; j < 8; j++)
        t8[j] = (short)f2bf_rne(R[(long)(k0 + j) * 1024 + col]);
      w[nt][cc] = t8;
    }
  }

  __shared__ float red[32 * 264];       // k-split reduce: 33.8 KB, padded
  __shared__ float xbuf[16 * 132];      // col->row transpose: 8.25 KB

  // ---- reduce/output mapping: thread owns (col nw, rows mg*4+0..3)
  const int nw = tid & 127;
  const int mg = tid >> 7;
  const int kglob = colbase + nw;
  const int ntr = nw >> 4;              // = nh*4 + nt of my column
  const int rlane = mg * 16 + (nw & 15);
  // ---- pack/store mapping: thread owns unit (m = tid&15, kqL = tid>>4)
  const int pm = tid & 15;
  const int pkq = tid >> 4;             // 0..31 (k quad within WG)
  const size_t punit = (size_t)((cg * 32 + pkq) * 16 + pm) * 16;
  // ---- consumer per-lane poll base (bytes within a (slot,cluster) block):
  //   unit (m=lr, kq = ks*64 + cc*8 + q*2 + s) -> 4 bases x 4 imm offsets
  const size_t cbase = (size_t)ks * 16384 + q * 512 + lr * 16;

  float* opb0 = out + ((long)(cluster * 16 + mg * 4 + 0) * 512) * 1024 + kglob;
  float* opb1 = out + ((long)(cluster * 16 + mg * 4 + 1) * 512) * 1024 + kglob;
  float* opb2 = out + ((long)(cluster * 16 + mg * 4 + 2) * 512) * 1024 + kglob;
  float* opb3 = out + ((long)(cluster * 16 + mg * 4 + 3) * 512) * 1024 + kglob;

  for (int t = 0; t < 512; ++t) {
    const long tOff = (long)t * 1024;
    // xk prefetch (plain cached loads; RT hides under the poll)
    const float xk0 = opb0[tOff];
    const float xk1 = opb1[tOff];
    const float xk2 = opb2[tOff];
    const float xk3 = opb3[tOff];

    f32x4 acc[4];
#pragma unroll
    for (int nt = 0; nt < 4; nt++) acc[nt] = (f32x4)0.f;

    if (t > 0) {
      const unsigned tag = ((unsigned)(t - 1) >> 1) & 15u;
      const unsigned E0 = ((tag & 1u) << 15) | (((tag >> 1) & 1u) << 31);
      const unsigned E1 = (((tag >> 2) & 1u) << 15) | (((tag >> 3) & 1u) << 31);
      const unsigned char* blk =
          hbuf + (size_t)(((t - 1) & 1) * 4 + cluster) * 65536 + cbase;
      const unsigned char* b0 = blk;
      const unsigned char* b1 = blk + 4096;
      const unsigned char* b2 = blk + 8192;
      const unsigned char* b3 = blk + 12288;
      u32x4 U[16];
      // poll: reload own 16 units until every hi sign nibble matches tag
      for (;;) {
        asm volatile(
            "global_load_dwordx4 %0,  %16, off sc0 sc1\n\t"
            "global_load_dwordx4 %1,  %16, off offset:256 sc0 sc1\n\t"
            "global_load_dwordx4 %2,  %16, off offset:2048 sc0 sc1\n\t"
            "global_load_dwordx4 %3,  %16, off offset:2304 sc0 sc1\n\t"
            "global_load_dwordx4 %4,  %17, off sc0 sc1\n\t"
            "global_load_dwordx4 %5,  %17, off offset:256 sc0 sc1\n\t"
            "global_load_dwordx4 %6,  %17, off offset:2048 sc0 sc1\n\t"
            "global_load_dwordx4 %7,  %17, off offset:2304 sc0 sc1\n\t"
            "global_load_dwordx4 %8,  %18, off sc0 sc1\n\t"
            "global_load_dwordx4 %9,  %18, off offset:256 sc0 sc1\n\t"
            "global_load_dwordx4 %10, %18, off offset:2048 sc0 sc1\n\t"
            "global_load_dwordx4 %11, %18, off offset:2304 sc0 sc1\n\t"
            "global_load_dwordx4 %12, %19, off sc0 sc1\n\t"
            "global_load_dwordx4 %13, %19, off offset:256 sc0 sc1\n\t"
            "global_load_dwordx4 %14, %19, off offset:2048 sc0 sc1\n\t"
            "global_load_dwordx4 %15, %19, off offset:2304 sc0 sc1\n\t"
            "s_waitcnt vmcnt(0)"
            : "=&v"(U[0]), "=&v"(U[1]), "=&v"(U[2]), "=&v"(U[3]),
              "=&v"(U[4]), "=&v"(U[5]), "=&v"(U[6]), "=&v"(U[7]),
              "=&v"(U[8]), "=&v"(U[9]), "=&v"(U[10]), "=&v"(U[11]),
              "=&v"(U[12]), "=&v"(U[13]), "=&v"(U[14]), "=&v"(U[15])
            : "v"(b0), "v"(b1), "v"(b2), "v"(b3)
            : "memory");
        unsigned bad = 0u;
#pragma unroll
        for (int i = 0; i < 16; i++)
          bad |= ((U[i][0] ^ E0) | (U[i][1] ^ E1)) & 0x80008000u;
        if (__ballot(bad != 0u) == 0ull) break;
      }
      // units valid: strip tag signs, build hi/lo frags, MFMA
#pragma unroll
      for (int cc = 0; cc < 8; cc++) {
        const int i0 = (cc >> 1) * 4 + (cc & 1) * 2;  // (cc, s=0); +1 = s=1
        u32x4 hivec, lovec;
        hivec[0] = U[i0][0] & 0x7fff7fffu;
        hivec[1] = U[i0][1] & 0x7fff7fffu;
        hivec[2] = U[i0 + 1][0] & 0x7fff7fffu;
        hivec[3] = U[i0 + 1][1] & 0x7fff7fffu;
        lovec[0] = U[i0][2];
        lovec[1] = U[i0][3];
        lovec[2] = U[i0 + 1][2];
        lovec[3] = U[i0 + 1][3];
        short8 ah = *(short8*)&hivec;
        short8 al = *(short8*)&lovec;
#pragma unroll
        for (int nt = 0; nt < 4; nt++) {
          acc[nt] = __builtin_amdgcn_mfma_f32_16x16x32_bf16(ah, w[nt][cc], acc[nt], 0, 0, 0);
          acc[nt] = __builtin_amdgcn_mfma_f32_16x16x32_bf16(al, w[nt][cc], acc[nt], 0, 0, 0);
        }
      }
    }

    // ---- 4-way k-split reduce through LDS (conflict-free b128 both ways)
#pragma unroll
    for (int nt = 0; nt < 4; nt++)
      *(f32x4*)&red[(ks * 8 + nh * 4 + nt) * 264 + lane * 4] = acc[nt];
    __syncthreads();
    f32x4 s = *(const f32x4*)&red[(0 * 8 + ntr) * 264 + rlane * 4];
#pragma unroll
    for (int kq = 1; kq < 4; ++kq)
      s += *(const f32x4*)&red[(kq * 8 + ntr) * 264 + rlane * 4];

    const float xarr[4] = {xk0, xk1, xk2, xk3};
    float hv[4];
#pragma unroll
    for (int r = 0; r < 4; ++r) hv[r] = fmaxf(s[r] + xarr[r], 0.0f);
    // out stores (plain, private, off the release path)
    opb0[tOff] = hv[0];
    opb1[tOff] = hv[1];
    opb2[tOff] = hv[2];
    opb3[tOff] = hv[3];
    // transpose col-ownership -> row-ownership via LDS
#pragma unroll
    for (int r = 0; r < 4; ++r) xbuf[(mg * 4 + r) * 132 + nw] = hv[r];
    __syncthreads();
    const f32x4 v = *(const f32x4*)&xbuf[pm * 132 + pkq * 4];
    // pack 16B unit: hi x4 (sign=tag bit) | lo x4 (raw)
    const unsigned ptag = ((unsigned)t >> 1) & 15u;
    unsigned hw[4], lw[4];
#pragma unroll
    for (int j = 0; j < 4; ++j) {
      unsigned short hr = f2bf_rne(v[j]);              // sign 0 (h>=0)
      float hf = __uint_as_float(((unsigned)hr) << 16);
      hw[j] = (unsigned)hr | (((ptag >> j) & 1u) << 15);
      lw[j] = (unsigned)f2bf_rne(v[j] - hf);
    }
    u32x4 pk;
    pk[0] = hw[0] | (hw[1] << 16);
    pk[1] = hw[2] | (hw[3] << 16);
    pk[2] = lw[0] | (lw[1] << 16);
    pk[3] = lw[2] | (lw[3] << 16);
    unsigned char* pst = hbuf + (size_t)((t & 1) * 4 + cluster) * 65536 + punit;
    // one-way publish: no drain, no flag -- the tag rides in the data
    asm volatile("global_store_dwordx4 %0, %1, off sc0 sc1"
                 :: "v"(pst), "v"(pk) : "memory");
    // next iteration's red write is fenced from this step's red reads by
    // the xbuf barrier above; xbuf WAR is fenced by next step's red barrier.
  }
}

extern "C" void kernel_launch(void* const* d_in, const int* in_sizes, int n_in,
                              void* d_out, int out_size, void* d_ws, size_t ws_size,
                              hipStream_t stream) {
  const float* x = (const float*)d_in[0];
  const float* kern = (const float*)d_in[1];
  const float* R = (const float*)d_in[2];
  float* out = (float*)d_out;

  // ws: [0, 512KB) h unit buffers [slot 2][cluster 4][64KB].
  // 0xFF fill => every unit reads as tag 15; live tags start at 0 and a
  // unit can only still be virgin/prior-run (tag 15) while consumers
  // expect tags 0..14 (t < 30), so no false-valid is possible.
  unsigned char* hbuf = (unsigned char*)d_ws;
  hipMemsetAsync(hbuf, 0xFF, (size_t)2 * 4 * 65536, stream);

  dim3 g1(8, 256), b1(256);
  xproj_kernel<<<g1, b1, 0, stream>>>(x, kern, out);
  rnn_scan_kernel<<<32, 512, 0, stream>>>(R, out, hbuf);
}